// Round 2
// baseline (638.304 us; speedup 1.0000x reference)
//
#include <hip/hip_runtime.h>
#include <hip/hip_bf16.h>

using s8v   = __attribute__((ext_vector_type(8))) short;
using f32x4 = __attribute__((ext_vector_type(4))) float;

#define N_TOT 100352      // 32*56*56
#define WT_ELEMS 589824   // 3*256*768
#define XT_ELEMS 27557888 // 32*58*58*256
#define WS_NEED  56295424 // 2*(WT_ELEMS+XT_ELEMS)

__device__ __forceinline__ unsigned short f2bf(float f) {
    unsigned int u = __float_as_uint(f);
    unsigned int r = (u + 0x7FFF + ((u >> 16) & 1)) >> 16;  // RNE
    return (unsigned short)r;
}

// weights [O=256][C=256][9] fp32 -> Wt2 [dh=3][O=256][dw*256+c = 768] bf16
// For fixed dh, K=768 runs (dw,c) jointly == contiguous 3-pixel NHWC span in Xt.
__global__ void prep_w(const float* __restrict__ w, unsigned short* __restrict__ wt) {
    int idx = blockIdx.x * 256 + threadIdx.x;   // 0..589823
    int dh  = idx / 196608;
    int rem = idx - dh * 196608;
    int o   = rem / 768;
    int k   = rem - o * 768;
    int dw  = k >> 8;
    int c   = k & 255;
    wt[idx] = f2bf(w[(o * 256 + c) * 9 + dh * 3 + dw]);
}

// x [32][256][56][56] fp32 -> Xt [32][58][58][256] bf16, zero-padded NHWC
__global__ void prep_x(const float* __restrict__ x, unsigned short* __restrict__ xt) {
    int b  = blockIdx.x / 58;
    int hp = blockIdx.x % 58;
    int tid = threadIdx.x;
    unsigned short* rowout = xt + (size_t)(b * 58 + hp) * 58 * 256;
    if (hp == 0 || hp == 57) {
        uint4 z = {0u, 0u, 0u, 0u};
        uint4* p = (uint4*)rowout;
        for (int i = tid; i < 1856; i += 256) p[i] = z;   // 58*512B
        return;
    }
    int h = hp - 1;
    __shared__ unsigned short lds[56 * 264];   // row stride 264 (pad) to break conflicts
    #pragma unroll
    for (int it = 0; it < 14; ++it) {
        int idx = it * 256 + tid;          // 0..3583 float4s
        int c  = idx / 14;
        int w4 = idx - c * 14;
        float4 v = *(const float4*)(x + (((size_t)(b * 256 + c) * 56 + h) * 56 + w4 * 4));
        int wb = w4 * 4;
        lds[(wb + 0) * 264 + c] = f2bf(v.x);
        lds[(wb + 1) * 264 + c] = f2bf(v.y);
        lds[(wb + 2) * 264 + c] = f2bf(v.z);
        lds[(wb + 3) * 264 + c] = f2bf(v.w);
    }
    __syncthreads();
    // zero edge pixels 0 and 57 (512B each)
    {
        unsigned int* z1 = (unsigned int*)rowout;            // pixel 0
        unsigned int* z2 = (unsigned int*)(rowout + 57 * 256);
        if (tid < 128) z1[tid] = 0u; else z2[tid - 128] = 0u;
    }
    // interior pixels 1..56: 2 pixels per iter, uint (2 c's) per lane
    int c2 = tid & 127;
    int ph = tid >> 7;
    for (int w = 0; w < 56; w += 2) {
        int pw = w + ph;
        unsigned int v = *(const unsigned int*)&lds[pw * 264 + c2 * 2];
        *(unsigned int*)(rowout + (pw + 1) * 256 + c2 * 2) = v;
    }
}

// Implicit GEMM, NO LDS, NO barriers: every MFMA fragment is a direct
// contiguous 16B global load. out[o][n] = sum_dh sum_{k<768} Wt2[dh][o][k] *
// Xt[rowbase(n)+dh*58 pixels][k]. 128x128 block tile, 4 waves, 4x4 frags/wave.
__global__ __launch_bounds__(256) void gemm_conv(const unsigned short* __restrict__ wt,
                                                 const unsigned short* __restrict__ xt,
                                                 float* __restrict__ out) {
    int bx = blockIdx.x;
    int mt = bx / 784;
    int rb = bx - mt * 784;
    int nt = (rb & 7) * 98 + (rb >> 3);   // XCD-contiguous nt ranges
    int tid  = threadIdx.x;
    int wave = tid >> 6, lane = tid & 63;
    int quad = lane >> 4, l16 = lane & 15;
    int wm = wave >> 1, wn = wave & 1;

    // A fragment bases: lane l16 -> o row, quad -> k-subchunk
    const unsigned short* pA[4];
    #pragma unroll
    for (int i = 0; i < 4; ++i) {
        int o = mt * 128 + wm * 64 + i * 16 + l16;
        pA[i] = wt + o * 768 + quad * 8;
    }
    // B fragment bases: lane l16 -> pixel n, quad -> k-subchunk
    const unsigned short* pB[4];
    #pragma unroll
    for (int j = 0; j < 4; ++j) {
        int n = nt * 128 + wn * 64 + j * 16 + l16;
        int b = n / 3136; int rr = n - b * 3136; int h = rr / 56; int w = rr - h * 56;
        pB[j] = xt + (((size_t)(b * 58 + h) * 58 + w) << 8) + quad * 8;
    }

    f32x4 acc[4][4] = {};

    for (int dh = 0; dh < 3; ++dh) {
        #pragma unroll 4
        for (int cb = 0; cb < 24; ++cb) {
            s8v af[4], bf[4];
            #pragma unroll
            for (int i = 0; i < 4; ++i) af[i] = *(const s8v*)(pA[i] + cb * 32);
            #pragma unroll
            for (int j = 0; j < 4; ++j) bf[j] = *(const s8v*)(pB[j] + cb * 32);
            #pragma unroll
            for (int i = 0; i < 4; ++i)
                #pragma unroll
                for (int j = 0; j < 4; ++j)
                    acc[i][j] = __builtin_amdgcn_mfma_f32_16x16x32_bf16(af[i], bf[j], acc[i][j], 0, 0, 0);
        }
        #pragma unroll
        for (int i = 0; i < 4; ++i) pA[i] += 196608;   // next dh slice of Wt2
        #pragma unroll
        for (int j = 0; j < 4; ++j) pB[j] += 58 * 256; // next padded image row
    }

    // Epilogue: C/D layout col=lane&15 (n), row=quad*4+reg (m=o)
    float* op = out + (size_t)(mt * 128 + wm * 64 + quad * 4) * N_TOT + nt * 128 + wn * 64 + l16;
    #pragma unroll
    for (int i = 0; i < 4; ++i)
        #pragma unroll
        for (int r = 0; r < 4; ++r) {
            float* orow = op + (size_t)(i * 16 + r) * N_TOT;
            #pragma unroll
            for (int j = 0; j < 4; ++j)
                orow[j * 16] = acc[i][j][r];
        }
}

// Fallback if workspace too small: direct conv, one thread per output.
__global__ void conv_naive(const float* __restrict__ x, const float* __restrict__ wq,
                           float* __restrict__ out) {
    int f = blockIdx.x * 256 + threadIdx.x;
    int o = f / N_TOT;
    int n = f - o * N_TOT;
    int b = n / 3136; int r = n - b * 3136; int h = r / 56; int w = r - h * 56;
    const float* xb = x + (size_t)b * 256 * 3136;
    const float* wo = wq + o * 2304;
    float acc = 0.f;
    for (int c = 0; c < 256; ++c) {
        const float* xc = xb + c * 3136;
        const float* wc = wo + c * 9;
        #pragma unroll
        for (int dh = 0; dh < 3; ++dh) {
            int ih = h + dh - 1;
            if (ih < 0 || ih >= 56) continue;
            const float* xr = xc + ih * 56;
            #pragma unroll
            for (int dw = 0; dw < 3; ++dw) {
                int iw = w + dw - 1;
                if (iw >= 0 && iw < 56) acc += xr[iw] * wc[dh * 3 + dw];
            }
        }
    }
    out[f] = acc;
}

extern "C" void kernel_launch(void* const* d_in, const int* in_sizes, int n_in,
                              void* d_out, int out_size, void* d_ws, size_t ws_size,
                              hipStream_t stream) {
    const float* x = (const float*)d_in[0];
    const float* w = (const float*)d_in[1];
    float* out = (float*)d_out;
    if (ws_size >= (size_t)WS_NEED) {
        unsigned short* wt = (unsigned short*)d_ws;
        unsigned short* xt = wt + WT_ELEMS;
        prep_w<<<2304, 256, 0, stream>>>(w, wt);
        prep_x<<<32 * 58, 256, 0, stream>>>(x, xt);
        gemm_conv<<<1568, 256, 0, stream>>>(wt, xt, out);
    } else {
        conv_naive<<<N_TOT, 256, 0, stream>>>(x, w, out);
    }
}

// Round 3
// 371.323 us; speedup vs baseline: 1.7190x; 1.7190x over previous
//
#include <hip/hip_runtime.h>
#include <hip/hip_bf16.h>

using s8v   = __attribute__((ext_vector_type(8))) short;
using f32x4 = __attribute__((ext_vector_type(4))) float;

#define N_TOT 100352              // 32*56*56
#define WT_ELEMS 589824           // 2*72*4*128*8
#define PLANE_ELEMS 861184        // 32*58*58*8 (one channel-group plane)
#define XT_ELEMS 27557888         // 32 planes
#define WS_NEED  56295424         // 2*(WT_ELEMS+XT_ELEMS)

__device__ __forceinline__ unsigned short f2bf(float f) {
    unsigned int u = __float_as_uint(f);
    unsigned int r = (u + 0x7FFF + ((u >> 16) & 1)) >> 16;  // RNE
    return (unsigned short)r;
}

__device__ __forceinline__ void gl_lds16(const void* g, void* l) {
    __builtin_amdgcn_global_load_lds(
        (const __attribute__((address_space(1))) unsigned int*)g,
        (__attribute__((address_space(3))) unsigned int*)l, 16, 0, 0);
}

// weights [O=256][C=256][9] fp32 -> Wt tiled [mt=2][kb=72][chunk=4][row=128][8] bf16
// kb = tap*8 + cb; K element (kb,chunk,sub) -> channel c = cb*32+chunk*8+sub at tap.
__global__ void prep_w(const float* __restrict__ w, unsigned short* __restrict__ wt) {
    int idx = blockIdx.x * 256 + threadIdx.x;   // 0..589823
    int sub   = idx & 7;
    int row   = (idx >> 3) & 127;
    int chunk = (idx >> 10) & 3;
    int kb    = (idx >> 12) % 72;
    int mt    = idx / 294912;
    int tap = kb >> 3, cb = kb & 7;
    int c = cb * 32 + chunk * 8 + sub;
    int o = mt * 128 + row;
    wt[idx] = f2bf(w[(o * 256 + c) * 9 + tap]);
}

// x [32][256][56][56] fp32 -> Xt3 [cg=32][b=32][hp=58][wp=58][8ch] bf16, zero-padded
__global__ void prep_x(const float* __restrict__ x, unsigned short* __restrict__ xt) {
    int b  = blockIdx.x / 58;
    int hp = blockIdx.x % 58;
    int tid = threadIdx.x;
    uint4 zero = {0u, 0u, 0u, 0u};
    size_t rowbase = (size_t)(b * 58 + hp) * 58;   // pixel index of wp=0 in each plane
    if (hp == 0 || hp == 57) {
        for (int i = tid; i < 1856; i += 256) {
            int cg = i / 58, wp = i - cg * 58;
            *(uint4*)(xt + ((size_t)cg * PLANE_ELEMS + (rowbase + wp) * 8)) = zero;
        }
        return;
    }
    int h = hp - 1;
    __shared__ unsigned short lds[56 * 264];   // [w][c], row stride 264
    #pragma unroll
    for (int it = 0; it < 14; ++it) {
        int idx = it * 256 + tid;          // 0..3583 float4s
        int c  = idx / 14;
        int w4 = idx - c * 14;
        float4 v = *(const float4*)(x + (((size_t)(b * 256 + c) * 56 + h) * 56 + w4 * 4));
        int wb = w4 * 4;
        lds[(wb + 0) * 264 + c] = f2bf(v.x);
        lds[(wb + 1) * 264 + c] = f2bf(v.y);
        lds[(wb + 2) * 264 + c] = f2bf(v.z);
        lds[(wb + 3) * 264 + c] = f2bf(v.w);
    }
    __syncthreads();
    for (int i = tid; i < 1856; i += 256) {
        int cg = i / 58, wp = i - cg * 58;
        uint4 v;
        if (wp == 0 || wp == 57) v = zero;
        else v = *(const uint4*)&lds[(wp - 1) * 264 + cg * 8];
        *(uint4*)(xt + ((size_t)cg * PLANE_ELEMS + (rowbase + wp) * 8)) = v;
    }
}

// Implicit GEMM, m97 structure with fully-coalesced staging.
// out[o][n] = sum_{tap,c} W[o][c][tap] * Xpad[pix(n)+tap][c]
// 128x128 tile, BK=32, 4 waves, 4x4 16x16x32 frags each.
__global__ __launch_bounds__(256) void gemm_conv(const unsigned short* __restrict__ wt,
                                                 const unsigned short* __restrict__ xt,
                                                 float* __restrict__ out) {
    __shared__ __align__(16) char smA[8192];  // [chunk 0..3][row 0..127][16B]
    __shared__ __align__(16) char smB[8192];  // [chunk 0..3][pix 0..127][16B]
    int bx = blockIdx.x;
    int mt = bx / 784;
    int rb = bx - mt * 784;
    int nt = (rb & 7) * 98 + (rb >> 3);   // XCD-contiguous nt ranges
    int tid  = threadIdx.x;
    int wave = tid >> 6, lane = tid & 63;
    int quad = lane >> 4, l16 = lane & 15;
    int wm = wave >> 1, wn = wave & 1;

    // A staging source: tiled weights, contiguous per wave.
    const unsigned short* aSrc = wt + (size_t)mt * 294912 + wave * 1024 + lane * 8;
    char* ldsA0 = smA + wave * 2048;
    char* ldsB0 = smB + wave * 2048;

    // B staging: padded-pixel element offsets for n1 = nt*128+lane, n2 = n1+64
    int n1 = nt * 128 + lane;
    int b1 = n1 / 3136; int r1 = n1 - b1 * 3136; int h1 = r1 / 56; int w1 = r1 - h1 * 56;
    int n2 = n1 + 64;
    int b2 = n2 / 3136; int r2 = n2 - b2 * 3136; int h2 = r2 / 56; int w2 = r2 - h2 * 56;
    size_t pix1 = (size_t)((b1 * 58 + h1) * 58 + w1) * 8;
    size_t pix2 = (size_t)((b2 * 58 + h2) * 58 + w2) * 8;

    const char* ra = smA + quad * 2048;
    const char* rb2 = smB + quad * 2048;

    f32x4 acc[4][4] = {};

    for (int tap = 0; tap < 9; ++tap) {
        int dh = tap / 3;
        int dw = tap - dh * 3;
        size_t tshift = (size_t)(dh * 58 + dw) * 8;
        for (int cb = 0; cb < 8; ++cb) {
            const unsigned short* plane = xt + (size_t)(cb * 4 + wave) * PLANE_ELEMS + tshift;
            gl_lds16(aSrc,        ldsA0);
            gl_lds16(aSrc + 512,  ldsA0 + 1024);
            gl_lds16(plane + pix1, ldsB0);
            gl_lds16(plane + pix2, ldsB0 + 1024);
            aSrc += 4096;
            __syncthreads();
            s8v af[4], bf[4];
            #pragma unroll
            for (int i = 0; i < 4; ++i)
                af[i] = *(const s8v*)(ra + ((wm * 64 + i * 16 + l16) << 4));
            #pragma unroll
            for (int j = 0; j < 4; ++j)
                bf[j] = *(const s8v*)(rb2 + ((wn * 64 + j * 16 + l16) << 4));
            #pragma unroll
            for (int i = 0; i < 4; ++i)
                #pragma unroll
                for (int j = 0; j < 4; ++j)
                    acc[i][j] = __builtin_amdgcn_mfma_f32_16x16x32_bf16(af[i], bf[j], acc[i][j], 0, 0, 0);
            __syncthreads();
        }
    }

    // Epilogue: C/D layout col=lane&15 (n), row=quad*4+reg (m=o)
    float* op = out + (size_t)(mt * 128 + wm * 64 + quad * 4) * N_TOT + nt * 128 + wn * 64 + l16;
    #pragma unroll
    for (int i = 0; i < 4; ++i)
        #pragma unroll
        for (int r = 0; r < 4; ++r) {
            float* orow = op + (size_t)(i * 16 + r) * N_TOT;
            #pragma unroll
            for (int j = 0; j < 4; ++j)
                orow[j * 16] = acc[i][j][r];
        }
}

// Fallback if workspace too small: direct conv, one thread per output.
__global__ void conv_naive(const float* __restrict__ x, const float* __restrict__ wq,
                           float* __restrict__ out) {
    int f = blockIdx.x * 256 + threadIdx.x;
    int o = f / N_TOT;
    int n = f - o * N_TOT;
    int b = n / 3136; int r = n - b * 3136; int h = r / 56; int w = r - h * 56;
    const float* xb = x + (size_t)b * 256 * 3136;
    const float* wo = wq + o * 2304;
    float acc = 0.f;
    for (int c = 0; c < 256; ++c) {
        const float* xc = xb + c * 3136;
        const float* wc = wo + c * 9;
        #pragma unroll
        for (int dh = 0; dh < 3; ++dh) {
            int ih = h + dh - 1;
            if (ih < 0 || ih >= 56) continue;
            const float* xr = xc + ih * 56;
            #pragma unroll
            for (int dw = 0; dw < 3; ++dw) {
                int iw = w + dw - 1;
                if (iw >= 0 && iw < 56) acc += xr[iw] * wc[dh * 3 + dw];
            }
        }
    }
    out[f] = acc;
}

extern "C" void kernel_launch(void* const* d_in, const int* in_sizes, int n_in,
                              void* d_out, int out_size, void* d_ws, size_t ws_size,
                              hipStream_t stream) {
    const float* x = (const float*)d_in[0];
    const float* w = (const float*)d_in[1];
    float* out = (float*)d_out;
    if (ws_size >= (size_t)WS_NEED) {
        unsigned short* wt = (unsigned short*)d_ws;
        unsigned short* xt = wt + WT_ELEMS;
        prep_w<<<2304, 256, 0, stream>>>(w, wt);
        prep_x<<<32 * 58, 256, 0, stream>>>(x, xt);
        gemm_conv<<<1568, 256, 0, stream>>>(wt, xt, out);
    } else {
        conv_naive<<<N_TOT, 256, 0, stream>>>(x, w, out);
    }
}

// Round 4
// 361.800 us; speedup vs baseline: 1.7642x; 1.0263x over previous
//
#include <hip/hip_runtime.h>
#include <hip/hip_bf16.h>

using s8v   = __attribute__((ext_vector_type(8))) short;
using f32x4 = __attribute__((ext_vector_type(4))) float;

#define N_TOT 100352              // 32*56*56
#define WT_ELEMS 589824           // 2*72*4*128*8
#define PLANE_ELEMS 861184        // 32*58*58*8 (one channel-group plane)
#define XT_ELEMS 27557888         // 32 planes
#define WS_NEED  56295424         // 2*(WT_ELEMS+XT_ELEMS)

__device__ __forceinline__ unsigned short f2bf(float f) {
    unsigned int u = __float_as_uint(f);
    unsigned int r = (u + 0x7FFF + ((u >> 16) & 1)) >> 16;  // RNE
    return (unsigned short)r;
}

__device__ __forceinline__ void gl_lds16(const void* g, void* l) {
    __builtin_amdgcn_global_load_lds(
        (const __attribute__((address_space(1))) unsigned int*)g,
        (__attribute__((address_space(3))) unsigned int*)l, 16, 0, 0);
}

// weights [O=256][C=256][9] fp32 -> Wt tiled [mt=2][cb=8][tap=9][chunk=4][row=128][8]
// (tap innermost among K-blocks so the gemm's cb-outer/tap-inner walk is linear)
__global__ void prep_w(const float* __restrict__ w, unsigned short* __restrict__ wt) {
    int idx = blockIdx.x * 256 + threadIdx.x;   // 0..589823
    int sub   = idx & 7;
    int row   = (idx >> 3) & 127;
    int chunk = (idx >> 10) & 3;
    int kb    = (idx >> 12) % 72;
    int mt    = idx / 294912;
    int cb = kb / 9, tap = kb - cb * 9;
    int c = cb * 32 + chunk * 8 + sub;
    int o = mt * 128 + row;
    wt[idx] = f2bf(w[(o * 256 + c) * 9 + tap]);
}

// x [32][256][56][56] fp32 -> Xt [cg=32][b=32][hp=58][wp=58][8ch] bf16, zero-padded.
// LDS-free: one wave per (cg) per (b,h): 8 coalesced channel-row loads -> pack -> one
// contiguous 928B row store per wave.
__global__ void prep_x(const float* __restrict__ x, unsigned short* __restrict__ xt) {
    int b  = blockIdx.x / 58;
    int hp = blockIdx.x % 58;
    int tid = threadIdx.x;
    uint4 zero = {0u, 0u, 0u, 0u};
    size_t rowbase = (size_t)(b * 58 + hp) * 58;   // pixel index of wp=0 in each plane
    if (hp == 0 || hp == 57) {
        for (int i = tid; i < 1856; i += 256) {
            int cg = i / 58, wp = i - cg * 58;
            *(uint4*)(xt + ((size_t)cg * PLANE_ELEMS + (rowbase + wp) * 8)) = zero;
        }
        return;
    }
    int h = hp - 1;
    int wave = tid >> 6, lane = tid & 63;
    for (int cg = wave; cg < 32; cg += 4) {
        unsigned short* outp = xt + (size_t)cg * PLANE_ELEMS + rowbase * 8;
        if (lane < 56) {
            const float* src = x + ((size_t)(b * 256 + cg * 8) * 3136 + h * 56 + lane);
            unsigned int p[4];
            #pragma unroll
            for (int q = 0; q < 4; ++q) {
                float f0 = src[(size_t)(2 * q) * 3136];
                float f1 = src[(size_t)(2 * q + 1) * 3136];
                p[q] = (unsigned)f2bf(f0) | ((unsigned)f2bf(f1) << 16);
            }
            *(uint4*)(outp + (size_t)(lane + 1) * 8) = *(uint4*)p;
        } else if (lane == 56) {
            *(uint4*)outp = zero;              // wp = 0 pad
        } else if (lane == 57) {
            *(uint4*)(outp + 57 * 8) = zero;   // wp = 57 pad
        }
    }
}

// Implicit GEMM, m97 structure, coalesced staging, tap-INNER loop for Xt L2 reuse.
// out[o][n] = sum_{tap,c} W[o][c][tap] * Xpad[pix(n)+tap][c]
// 128x128 tile, BK=32, 4 waves, 4x4 16x16x32 frags each.
__global__ __launch_bounds__(256) void gemm_conv(const unsigned short* __restrict__ wt,
                                                 const unsigned short* __restrict__ xt,
                                                 float* __restrict__ out) {
    __shared__ __align__(16) char smA[8192];  // [chunk 0..3][row 0..127][16B]
    __shared__ __align__(16) char smB[8192];  // [chunk 0..3][pix 0..127][16B]
    int bx = blockIdx.x;
    int mt = bx / 784;
    int rb = bx - mt * 784;
    int nt = (rb & 7) * 98 + (rb >> 3);   // XCD-contiguous nt ranges
    int tid  = threadIdx.x;
    int wave = tid >> 6, lane = tid & 63;
    int quad = lane >> 4, l16 = lane & 15;
    int wm = wave >> 1, wn = wave & 1;

    // A staging source: tiled weights, contiguous per wave, linear walk.
    const unsigned short* aSrc = wt + (size_t)mt * 294912 + wave * 1024 + lane * 8;
    char* ldsA0 = smA + wave * 2048;
    char* ldsB0 = smB + wave * 2048;

    // B staging: padded-pixel element offsets for n1 = nt*128+lane, n2 = n1+64
    int n1 = nt * 128 + lane;
    int b1 = n1 / 3136; int r1 = n1 - b1 * 3136; int h1 = r1 / 56; int w1 = r1 - h1 * 56;
    int n2 = n1 + 64;
    int b2 = n2 / 3136; int r2 = n2 - b2 * 3136; int h2 = r2 / 56; int w2 = r2 - h2 * 56;
    size_t pix1 = (size_t)((b1 * 58 + h1) * 58 + w1) * 8;
    size_t pix2 = (size_t)((b2 * 58 + h2) * 58 + w2) * 8;

    const char* ra  = smA + quad * 2048;
    const char* rb2 = smB + quad * 2048;

    f32x4 acc[4][4] = {};

    #pragma unroll 1
    for (int cb = 0; cb < 8; ++cb) {
        const unsigned short* pl1 = xt + (size_t)(cb * 4 + wave) * PLANE_ELEMS + pix1;
        const unsigned short* pl2 = xt + (size_t)(cb * 4 + wave) * PLANE_ELEMS + pix2;
        #pragma unroll
        for (int dh = 0; dh < 3; ++dh) {
            #pragma unroll
            for (int dw = 0; dw < 3; ++dw) {
                int tsh = (dh * 58 + dw) * 8;     // 1-pixel shifts: L1/L2 hits across taps
                gl_lds16(aSrc,        ldsA0);
                gl_lds16(aSrc + 512,  ldsA0 + 1024);
                gl_lds16(pl1 + tsh,   ldsB0);
                gl_lds16(pl2 + tsh,   ldsB0 + 1024);
                aSrc += 4096;
                __syncthreads();
                s8v af[4], bf[4];
                #pragma unroll
                for (int i = 0; i < 4; ++i)
                    af[i] = *(const s8v*)(ra + ((wm * 64 + i * 16 + l16) << 4));
                #pragma unroll
                for (int j = 0; j < 4; ++j)
                    bf[j] = *(const s8v*)(rb2 + ((wn * 64 + j * 16 + l16) << 4));
                #pragma unroll
                for (int i = 0; i < 4; ++i)
                    #pragma unroll
                    for (int j = 0; j < 4; ++j)
                        acc[i][j] = __builtin_amdgcn_mfma_f32_16x16x32_bf16(af[i], bf[j], acc[i][j], 0, 0, 0);
                __syncthreads();
            }
        }
    }

    // Epilogue: C/D layout col=lane&15 (n), row=quad*4+reg (m=o)
    float* op = out + (size_t)(mt * 128 + wm * 64 + quad * 4) * N_TOT + nt * 128 + wn * 64 + l16;
    #pragma unroll
    for (int i = 0; i < 4; ++i)
        #pragma unroll
        for (int r = 0; r < 4; ++r) {
            float* orow = op + (size_t)(i * 16 + r) * N_TOT;
            #pragma unroll
            for (int j = 0; j < 4; ++j)
                orow[j * 16] = acc[i][j][r];
        }
}

// Fallback if workspace too small: direct conv, one thread per output.
__global__ void conv_naive(const float* __restrict__ x, const float* __restrict__ wq,
                           float* __restrict__ out) {
    int f = blockIdx.x * 256 + threadIdx.x;
    int o = f / N_TOT;
    int n = f - o * N_TOT;
    int b = n / 3136; int r = n - b * 3136; int h = r / 56; int w = r - h * 56;
    const float* xb = x + (size_t)b * 256 * 3136;
    const float* wo = wq + o * 2304;
    float acc = 0.f;
    for (int c = 0; c < 256; ++c) {
        const float* xc = xb + c * 3136;
        const float* wc = wo + c * 9;
        #pragma unroll
        for (int dh = 0; dh < 3; ++dh) {
            int ih = h + dh - 1;
            if (ih < 0 || ih >= 56) continue;
            const float* xr = xc + ih * 56;
            #pragma unroll
            for (int dw = 0; dw < 3; ++dw) {
                int iw = w + dw - 1;
                if (iw >= 0 && iw < 56) acc += xr[iw] * wc[dh * 3 + dw];
            }
        }
    }
    out[f] = acc;
}

extern "C" void kernel_launch(void* const* d_in, const int* in_sizes, int n_in,
                              void* d_out, int out_size, void* d_ws, size_t ws_size,
                              hipStream_t stream) {
    const float* x = (const float*)d_in[0];
    const float* w = (const float*)d_in[1];
    float* out = (float*)d_out;
    if (ws_size >= (size_t)WS_NEED) {
        unsigned short* wt = (unsigned short*)d_ws;
        unsigned short* xt = wt + WT_ELEMS;
        prep_w<<<2304, 256, 0, stream>>>(w, wt);
        prep_x<<<32 * 58, 256, 0, stream>>>(x, xt);
        gemm_conv<<<1568, 256, 0, stream>>>(wt, xt, out);
    } else {
        conv_naive<<<N_TOT, 256, 0, stream>>>(x, w, out);
    }
}